// Round 1
// baseline (86.301 us; speedup 1.0000x reference)
//
#include <hip/hip_runtime.h>

// x: [2, 8, 128, 128, 128] fp32
// attentions: [2, 8, 512, 1] fp32
// out: out0 [2,8,128,128,128] ++ out1(correction) [2,8,128,128,128], fp32
//
// adj[b,c,p,q,r] = (# voxels in 8^3 block (p,q,r) whose channel-argmax == c) / 512
// corr[b,c,D,H,W] = att[b,c,(D/16*8+H/16)*8+W/16] * adj[b,c, D%16, H%16, W%16]
// y = x + corr*x ; out0 = y + corr*y ; out1 = corr

#define PLANE (128 * 128 * 128)   // per-channel voxel count = 2,097,152

// ---------------- Pass 1: argmax-histogram -> adj (in d_ws) ----------------
// One workgroup per (b, p, q): slab z in [8p,8p+8), y in [8q,8q+8), all x, all c.
// Each adj bin (b,c,p,q,r) is owned by exactly one workgroup -> plain stores.
__global__ __launch_bounds__(256) void dpaa_pass1_hist(const float* __restrict__ x,
                                                       float* __restrict__ adj) {
    const int bid = blockIdx.x;        // [0, 2*16*16)
    const int b = bid >> 8;
    const int p = (bid >> 4) & 15;
    const int q = bid & 15;
    const int tid = threadIdx.x;

    __shared__ int cnt[8][16];         // [channel][r-bin]
    if (tid < 128) cnt[tid >> 4][tid & 15] = 0;
    __syncthreads();

    const float* xb = x + b * 8 * PLANE + (p * 8) * 16384 + (q * 8) * 128;

    #pragma unroll
    for (int k = 0; k < 8; ++k) {
        const int g    = tid + k * 256;   // float4-group in slab, [0,2048)
        const int xg   = g & 31;          // x/4
        const int yloc = (g >> 5) & 7;
        const int zloc = g >> 8;          // [0,8)
        const int base = zloc * 16384 + yloc * 128 + (xg << 2);

        float4 v = *reinterpret_cast<const float4*>(xb + base);
        float bv0 = v.x, bv1 = v.y, bv2 = v.z, bv3 = v.w;
        int c0 = 0, c1 = 0, c2 = 0, c3 = 0;
        #pragma unroll
        for (int c = 1; c < 8; ++c) {
            float4 u = *reinterpret_cast<const float4*>(xb + c * PLANE + base);
            if (u.x > bv0) { bv0 = u.x; c0 = c; }   // strict > keeps first max (jnp.argmax)
            if (u.y > bv1) { bv1 = u.y; c1 = c; }
            if (u.z > bv2) { bv2 = u.z; c2 = c; }
            if (u.w > bv3) { bv3 = u.w; c3 = c; }
        }
        const int r = xg >> 1;            // x-bin = (4*xg)/8
        atomicAdd(&cnt[c0][r], 1);
        atomicAdd(&cnt[c1][r], 1);
        atomicAdd(&cnt[c2][r], 1);
        atomicAdd(&cnt[c3][r], 1);
    }
    __syncthreads();

    if (tid < 128) {
        const int c = tid >> 4, r = tid & 15;
        adj[(b * 8 + c) * 4096 + p * 256 + q * 16 + r] =
            (float)cnt[c][r] * (1.0f / 512.0f);
    }
}

// ---------------- Pass 2: apply correction ----------------
__global__ __launch_bounds__(256) void dpaa_pass2_apply(const float* __restrict__ x,
                                                        const float* __restrict__ att,
                                                        const float* __restrict__ adj,
                                                        float* __restrict__ out) {
    const int g = blockIdx.x * 256 + threadIdx.x;   // float4-group, [0, 8388608)
    const int bc  = g >> 19;                        // (b*8 + c), per-bc groups = 2^19
    const int rem = g & ((1 << 19) - 1);
    const int Wg  = rem & 31;                       // W/4
    const int H   = (rem >> 5) & 127;
    const int D   = rem >> 12;
    const int W0  = Wg << 2;

    const int kd = D & 15, kh = H & 15, kw = W0 & 15;
    const int d  = D >> 4, h  = H >> 4, w  = W0 >> 4;

    const float a = att[bc * 512 + ((d << 3) + h) * 8 + w];
    const float4 aj = *reinterpret_cast<const float4*>(adj + bc * 4096 + kd * 256 + kh * 16 + kw);
    const float4 xv = *reinterpret_cast<const float4*>(x + g * 4);

    float4 corr, o0;
    corr.x = a * aj.x; corr.y = a * aj.y; corr.z = a * aj.z; corr.w = a * aj.w;

    float y;
    y = xv.x + corr.x * xv.x;  o0.x = y + corr.x * y;
    y = xv.y + corr.y * xv.y;  o0.y = y + corr.y * y;
    y = xv.z + corr.z * xv.z;  o0.z = y + corr.z * y;
    y = xv.w + corr.w * xv.w;  o0.w = y + corr.w * y;

    *reinterpret_cast<float4*>(out + g * 4) = o0;
    *reinterpret_cast<float4*>(out + (2 * 8 * PLANE) + g * 4) = corr;
}

extern "C" void kernel_launch(void* const* d_in, const int* in_sizes, int n_in,
                              void* d_out, int out_size, void* d_ws, size_t ws_size,
                              hipStream_t stream) {
    const float* x   = (const float*)d_in[0];
    const float* att = (const float*)d_in[1];
    float* adj = (float*)d_ws;           // 2*8*4096 floats = 256 KiB
    float* out = (float*)d_out;

    dpaa_pass1_hist<<<2 * 16 * 16, 256, 0, stream>>>(x, adj);
    dpaa_pass2_apply<<<(2 * 8 * PLANE / 4) / 256, 256, 0, stream>>>(x, att, adj, out);
}

// Round 3
// 80.658 us; speedup vs baseline: 1.0700x; 1.0700x over previous
//
#include <hip/hip_runtime.h>

// x: [2, 8, 128, 128, 128] fp32
// attentions: [2, 8, 512, 1] fp32
// out: out0 [2,8,128,128,128] ++ out1(correction) [2,8,128,128,128], fp32
//
// adj[b,c,p,q,r] = (# voxels in 8^3 block (p,q,r) whose channel-argmax == c) / 512
// corr[b,c,D,H,W] = att[b,c,(D/16*8+H/16)*8+W/16] * adj[b,c, D%16, H%16, W%16]
// y = x + corr*x ; out0 = y + corr*y ; out1 = corr

#define PLANE (128 * 128 * 128)   // per-channel voxel count = 2,097,152

typedef float v4f __attribute__((ext_vector_type(4)));

// ---------------- Pass 1: argmax-histogram -> adj (in d_ws) ----------------
// One workgroup per (b, p, q): slab z in [8p,8p+8), y in [8q,8q+8), all x, all c.
// Each adj bin (b,c,p,q,r) is owned by exactly one workgroup -> plain stores.
__global__ __launch_bounds__(256) void dpaa_pass1_hist(const float* __restrict__ x,
                                                       float* __restrict__ adj) {
    const int bid = blockIdx.x;        // [0, 2*16*16)
    const int b = bid >> 8;
    const int p = (bid >> 4) & 15;
    const int q = bid & 15;
    const int tid = threadIdx.x;

    __shared__ int cnt[8][16];         // [channel][r-bin]
    if (tid < 128) cnt[tid >> 4][tid & 15] = 0;
    __syncthreads();

    const float* xb = x + b * 8 * PLANE + (p * 8) * 16384 + (q * 8) * 128;

    #pragma unroll
    for (int k = 0; k < 8; ++k) {
        const int g    = tid + k * 256;   // float4-group in slab, [0,2048)
        const int xg   = g & 31;          // x/4
        const int yloc = (g >> 5) & 7;
        const int zloc = g >> 8;          // [0,8)
        const int base = zloc * 16384 + yloc * 128 + (xg << 2);

        v4f v = *reinterpret_cast<const v4f*>(xb + base);
        float bv0 = v.x, bv1 = v.y, bv2 = v.z, bv3 = v.w;
        int c0 = 0, c1 = 0, c2 = 0, c3 = 0;
        #pragma unroll
        for (int c = 1; c < 8; ++c) {
            v4f u = *reinterpret_cast<const v4f*>(xb + c * PLANE + base);
            if (u.x > bv0) { bv0 = u.x; c0 = c; }   // strict > keeps first max (jnp.argmax)
            if (u.y > bv1) { bv1 = u.y; c1 = c; }
            if (u.z > bv2) { bv2 = u.z; c2 = c; }
            if (u.w > bv3) { bv3 = u.w; c3 = c; }
        }
        const int r = xg >> 1;            // x-bin = (4*xg)/8
        atomicAdd(&cnt[c0][r], 1);
        atomicAdd(&cnt[c1][r], 1);
        atomicAdd(&cnt[c2][r], 1);
        atomicAdd(&cnt[c3][r], 1);
    }
    __syncthreads();

    if (tid < 128) {
        const int c = tid >> 4, r = tid & 15;
        adj[(b * 8 + c) * 4096 + p * 256 + q * 16 + r] =
            (float)cnt[c][r] * (1.0f / 512.0f);
    }
}

// ---------------- Pass 2: apply correction ----------------
// Non-temporal stores: the 268 MB of output must not evict x (134 MB, fully
// L3-resident after pass 1) ahead of the read pointer.
__global__ __launch_bounds__(256) void dpaa_pass2_apply(const float* __restrict__ x,
                                                        const float* __restrict__ att,
                                                        const float* __restrict__ adj,
                                                        float* __restrict__ out) {
    const int g = blockIdx.x * 256 + threadIdx.x;   // float4-group, [0, 8388608)
    const int bc  = g >> 19;                        // (b*8 + c), per-bc groups = 2^19
    const int rem = g & ((1 << 19) - 1);
    const int Wg  = rem & 31;                       // W/4
    const int H   = (rem >> 5) & 127;
    const int D   = rem >> 12;
    const int W0  = Wg << 2;

    const int kd = D & 15, kh = H & 15, kw = W0 & 15;
    const int d  = D >> 4, h  = H >> 4, w  = W0 >> 4;

    const float a = att[bc * 512 + ((d << 3) + h) * 8 + w];
    const v4f aj = *reinterpret_cast<const v4f*>(adj + bc * 4096 + kd * 256 + kh * 16 + kw);
    const v4f xv = *reinterpret_cast<const v4f*>(x + g * 4);

    v4f corr, o0;
    corr.x = a * aj.x; corr.y = a * aj.y; corr.z = a * aj.z; corr.w = a * aj.w;

    float y;
    y = xv.x + corr.x * xv.x;  o0.x = y + corr.x * y;
    y = xv.y + corr.y * xv.y;  o0.y = y + corr.y * y;
    y = xv.z + corr.z * xv.z;  o0.z = y + corr.z * y;
    y = xv.w + corr.w * xv.w;  o0.w = y + corr.w * y;

    __builtin_nontemporal_store(o0,   reinterpret_cast<v4f*>(out + g * 4));
    __builtin_nontemporal_store(corr, reinterpret_cast<v4f*>(out + (2 * 8 * PLANE) + g * 4));
}

extern "C" void kernel_launch(void* const* d_in, const int* in_sizes, int n_in,
                              void* d_out, int out_size, void* d_ws, size_t ws_size,
                              hipStream_t stream) {
    const float* x   = (const float*)d_in[0];
    const float* att = (const float*)d_in[1];
    float* adj = (float*)d_ws;           // 2*8*4096 floats = 256 KiB
    float* out = (float*)d_out;

    dpaa_pass1_hist<<<2 * 16 * 16, 256, 0, stream>>>(x, adj);
    dpaa_pass2_apply<<<(2 * 8 * PLANE / 4) / 256, 256, 0, stream>>>(x, att, adj, out);
}